// Round 6
// baseline (312.207 us; speedup 1.0000x reference)
//
#include <hip/hip_runtime.h>
#include <math.h>

typedef _Float16 f16x4 __attribute__((ext_vector_type(4)));
typedef _Float16 f16x2 __attribute__((ext_vector_type(2)));
typedef float    f32x4 __attribute__((ext_vector_type(4)));
typedef float    f32x2 __attribute__((ext_vector_type(2)));

constexpr int kT     = 512;   // sequence length
constexpr int kH     = 16;    // hidden
constexpr int kL     = 8;     // layers
constexpr int kNB    = 8;     // batch per block -> 256 blocks (full machine)
constexpr int kSlots = 8;     // ring depth (wall-indexed)
constexpr int kLyr   = kL + 1;          // region 0 = x, region l+1 = layer l h
constexpr int kRow   = 16;    // f16 per batch row (32 B, no pad: 2-way = free)
constexpr int kSlotE = kLyr * kNB * kRow;   // 1152 f16 = 2304 B per slot
constexpr int kIters = 33;    // 528 walls >= last useful wall 525

constexpr float kL2E = 1.4426950408889634f;

__device__ __forceinline__ float ex2(float w)  { return __builtin_amdgcn_exp2f(w); }
__device__ __forceinline__ float rcpf(float e) { return __builtin_amdgcn_rcpf(e); }

// Round-14: register-resident recurrence, full-machine grid.
//  - 8 waves = 8 layers; block = 8 batches; 256 blocks
//  - per-gate MFMA_p (16x16x16f16, p=0..3): A_p row m = W row
//    (m&3)*16 + 4*(m>>2) + p (scaled); B cols = 8 batches duplicated
//    (col n == col n+8). D: lane(n,q) reg r = gate r of (unit 4q+p, batch n&7)
//  - lane(n,q) owns cells p in {2hi, 2hi+1} (hi = n>>3): 2 cells, 14 trans
//  - B2 (= h(t-1) operand, elems jj = h[4q+jj]) assembled from own packed
//    pair + __shfl_xor(.,8) partner pair -> recurrence never touches LDS
//  - LDS only for cross-layer handoff: ds_write_b32 (h pair) +
//    ds_read_b64 (B1) per wave-step; 18432 B ring, wall-indexed slots
//  - skew 2 per layer (t = w - 2l), one s_barrier per wall,
//    lgkmcnt-only drain (vmcnt / x prefetch spans barriers, 4-wall depth)
//  - 7-trans activation with round-3's proven clamps (40/40/40/60)
__global__ __launch_bounds__(512, 2)
void lstm_rr8(const float* __restrict__ x,
              const float* __restrict__ Wih, const float* __restrict__ Whh,
              const float* __restrict__ bih, const float* __restrict__ bhh,
              const float* __restrict__ Wp,  const float* __restrict__ bpos,
              const float* __restrict__ Wo,  const float* __restrict__ bori,
              float* __restrict__ out)
{
    const int tid  = threadIdx.x;
    const int l    = tid >> 6;        // wave = layer
    const int lane = tid & 63;
    const int n    = lane & 15;       // MFMA row/col id
    const int q    = lane >> 4;       // k-quad
    const int b    = n & 7;           // batch (cols duplicated: n and n+8)
    const int hi   = n >> 3;          // which cell-pair this lane activates

    __shared__ __align__(16) _Float16 hb[kSlots][kLyr][kNB][kRow]; // 18432 B

    {   // zero-init LDS
        int* hz = (int*)&hb[0][0][0][0];
        for (int i = tid; i < (int)(sizeof(hb) / 4); i += 512) hz[i] = 0;
    }
    __syncthreads();

    // ---- A fragments: A_p row m=n -> W row (n&3)*16 + 4*(n>>2) + p,
    //      cols k = 4q..4q+3 (unit-identity contraction), gate-scaled ----
    const float asc = ((n & 3) == 2) ? (-2.0f * kL2E) : (-kL2E);
    f16x4 A1[4], A2[4];
    f32x4 bias[4];
    #pragma unroll
    for (int p = 0; p < 4; ++p) {
        const int wrow = (n & 3) * 16 + 4 * (n >> 2) + p;
        const float* w1 = Wih + (size_t)l * 64 * kH + wrow * kH + 4 * q;
        const float* w2 = Whh + (size_t)l * 64 * kH + wrow * kH + 4 * q;
        #pragma unroll
        for (int jj = 0; jj < 4; ++jj) {
            A1[p][jj] = (_Float16)(asc * w1[jj]);
            A2[p][jj] = (_Float16)(asc * w2[jj]);
        }
        #pragma unroll
        for (int r = 0; r < 4; ++r) {   // C-init: gate r of unit 4q+p
            const float sc = (r == 2) ? (-2.0f * kL2E) : (-kL2E);
            const int g0 = l * 64 + r * 16 + 4 * q + p;
            bias[p][r] = sc * (bih[g0] + bhh[g0]);
        }
    }

    // ---- LDS bases (slot offsets are compile-time multiples of kSlotE) ----
    const _Float16* b1base = &hb[0][l][b][4 * q];            // upstream (b64)
    _Float16* hwbase = &hb[0][l + 1][b][4 * q + 2 * hi];     // own h pair (b32)
    _Float16* xwbase = &hb[0][0][b][4 * q + 2 * hi];         // x pair (b32)

    // ---- x staging (wave 0): lane stages x[batch b][t][4q+2hi .. +1].
    //      x(tau) -> slot (tau-2)&7. Prime x(0)->slot6, x(1)->slot7;
    //      regs xr0..xr3 = x(2..5) (4-wall load-to-use distance) ----
    const float* xg = x + ((size_t)(blockIdx.x * kNB + b) * kT) * kH
                        + 4 * q + 2 * hi;
    f32x2 xr0 = {0.f, 0.f}, xr1 = {0.f, 0.f}, xr2 = {0.f, 0.f}, xr3 = {0.f, 0.f};
    if (l == 0) {
        #pragma unroll
        for (int t = 0; t < 2; ++t) {
            const f32x2 xv = *(const f32x2*)(xg + (size_t)t * kH);
            f16x2 xh = { (_Float16)xv[0], (_Float16)xv[1] };
            *(f16x2*)(&hb[6 + t][0][b][4 * q + 2 * hi]) = xh;
        }
        xr0 = *(const f32x2*)(xg + 2 * (size_t)kH);
        xr1 = *(const f32x2*)(xg + 3 * (size_t)kH);
        xr2 = *(const f32x2*)(xg + 4 * (size_t)kH);
        xr3 = *(const f32x2*)(xg + 5 * (size_t)kH);
    }
    __syncthreads();

    // ---- prime dIn ("wall -1" read, slot 6): x(0) for l=0, zeros for l>0 ----
    f32x4 dIn0, dIn1, dIn2, dIn3;
    {
        const f16x4 B1p = *(const f16x4*)(b1base + 6 * kSlotE);
        dIn0 = __builtin_amdgcn_mfma_f32_16x16x16f16(A1[0], B1p, bias[0], 0, 0, 0);
        dIn1 = __builtin_amdgcn_mfma_f32_16x16x16f16(A1[1], B1p, bias[1], 0, 0, 0);
        dIn2 = __builtin_amdgcn_mfma_f32_16x16x16f16(A1[2], B1p, bias[2], 0, 0, 0);
        dIn3 = __builtin_amdgcn_mfma_f32_16x16x16f16(A1[3], B1p, bias[3], 0, 0, 0);
    }

    f16x4 B2r = { (_Float16)0.f, (_Float16)0.f, (_Float16)0.f, (_Float16)0.f };
    float cA = 0.f, cB = 0.f;     // cell states for units 4q+2hi, 4q+2hi+1
    const int tl = 2 * l;

    #pragma unroll 1
    for (int it = 0; it < kIters; ++it) {
        const int wb = it * 16;
        #pragma unroll
        for (int k = 0; k < 16; ++k) {
            const int w = wb + k;
            const bool active = ((unsigned)(w - tl) < (unsigned)kT);

            // B1 for NEXT wall's dIn: upstream wrote at wall w-1 -> slot (k-1)&7
            const f16x4 B1n = *(const f16x4*)(b1base + ((k + 7) & 7) * kSlotE);

            // chain head: d_p = A2_p x h(t-1)[REGS] + dIn_p
            f32x4 d0 = __builtin_amdgcn_mfma_f32_16x16x16f16(A2[0], B2r, dIn0, 0, 0, 0);
            f32x4 d1 = __builtin_amdgcn_mfma_f32_16x16x16f16(A2[1], B2r, dIn1, 0, 0, 0);
            f32x4 d2 = __builtin_amdgcn_mfma_f32_16x16x16f16(A2[2], B2r, dIn2, 0, 0, 0);
            f32x4 d3 = __builtin_amdgcn_mfma_f32_16x16x16f16(A2[3], B2r, dIn3, 0, 0, 0);

            // select this lane's two cells (compile-time element indices)
            f32x4 dA, dB;
            #pragma unroll
            for (int r = 0; r < 4; ++r) {
                dA[r] = hi ? d2[r] : d0[r];     // cell unit 4q + 2hi
                dB[r] = hi ? d3[r] : d1[r];     // cell unit 4q + 2hi + 1
            }

            // ---- 7-trans cell updates (round-3 algebra + clamps) ----
            float hAf, hBf;
            {
                const float Ei = ex2(fminf(dA[0], 40.0f));
                const float Ef = ex2(fminf(dA[1], 40.0f));
                const float Eg = ex2(fminf(dA[2], 40.0f));
                const float Eo = ex2(fminf(dA[3], 60.0f));
                const float Dg = 1.0f + Eg;
                const float Df = 1.0f + Ef;
                const float P1  = fmaf(Ei, Dg, Dg);
                const float den = Df * P1;
                const float t2  = fmaf(-Eg, Df, Df);
                const float num = fmaf(cA, P1, t2);
                float cn = num * rcpf(den);
                cn = active ? cn : 0.0f;
                cA = cn;
                const float ac = fminf(cn * (-2.0f * kL2E), 60.0f);
                const float Ec = ex2(ac);
                const float Do = 1.0f + Eo;
                const float R2 = rcpf(fmaf(Do, Ec, Do));
                hAf = fmaf(-Ec, R2, R2);
            }
            {
                const float Ei = ex2(fminf(dB[0], 40.0f));
                const float Ef = ex2(fminf(dB[1], 40.0f));
                const float Eg = ex2(fminf(dB[2], 40.0f));
                const float Eo = ex2(fminf(dB[3], 60.0f));
                const float Dg = 1.0f + Eg;
                const float Df = 1.0f + Ef;
                const float P1  = fmaf(Ei, Dg, Dg);
                const float den = Df * P1;
                const float t2  = fmaf(-Eg, Df, Df);
                const float num = fmaf(cB, P1, t2);
                float cn = num * rcpf(den);
                cn = active ? cn : 0.0f;
                cB = cn;
                const float ac = fminf(cn * (-2.0f * kL2E), 60.0f);
                const float Ec = ex2(ac);
                const float Do = 1.0f + Eo;
                const float R2 = rcpf(fmaf(Do, Ec, Do));
                hBf = fmaf(-Ec, R2, R2);
            }

            // pack own pair; partner pair via lane^8; assemble full B2
            f16x2 hp = { (_Float16)hAf, (_Float16)hBf };
            union { f16x2 h; int i; } uh; uh.h = hp;
            const int own   = uh.i;
            const int other = __shfl_xor(own, 8, 64);
            union { int i[2]; f16x4 v; } ub;
            ub.i[0] = hi ? other : own;     // units 4q, 4q+1
            ub.i[1] = hi ? own : other;     // units 4q+2, 4q+3
            B2r = ub.v;                     // register recurrence

            // publish h(t) pair -> slot w&7 (downstream layer + head)
            *(f16x2*)(hwbase + (k & 7) * kSlotE) = hp;

            if (l == 0) {                   // publish x(w+2) -> slot w&7
                f16x2 xh = { (_Float16)xr0[0], (_Float16)xr0[1] };
                *(f16x2*)(xwbase + (k & 7) * kSlotE) = xh;
                xr0 = xr1; xr1 = xr2; xr2 = xr3;
                int tn = w + 6; if (tn > kT - 1) tn = kT - 1;
                xr3 = *(const f32x2*)(xg + (size_t)tn * kH);
            }

            // input half for next wall (off-chain), bias rides C
            dIn0 = __builtin_amdgcn_mfma_f32_16x16x16f16(A1[0], B1n, bias[0], 0, 0, 0);
            dIn1 = __builtin_amdgcn_mfma_f32_16x16x16f16(A1[1], B1n, bias[1], 0, 0, 0);
            dIn2 = __builtin_amdgcn_mfma_f32_16x16x16f16(A1[2], B1n, bias[2], 0, 0, 0);
            dIn3 = __builtin_amdgcn_mfma_f32_16x16x16f16(A1[3], B1n, bias[3], 0, 0, 0);

            // end of wall: drain DS writes, barrier (vmcnt stays in flight)
            asm volatile("s_waitcnt lgkmcnt(0)\n\ts_barrier" ::: "memory");
        }
    }

    __syncthreads();

    // ---- head: layer-7 h(511) written at wall 525 -> slot 525&7 = 5, region 8
    if (l == kL - 1 && lane < kNB) {
        const int bb = lane;
        float hreg[kH];
        #pragma unroll
        for (int u = 0; u < kH; ++u) hreg[u] = (float)hb[5][kL][bb][u];
        #pragma unroll
        for (int r = 0; r < 3; ++r) {
            float accP = bpos[r], accO = bori[r];
            #pragma unroll
            for (int u = 0; u < kH; ++u) {
                accP = fmaf(hreg[u], Wp[r * kH + u], accP);
                accO = fmaf(hreg[u], Wo[r * kH + u], accO);
            }
            const float Et = ex2(-2.0f * kL2E * accO);
            accO = fmaf(2.0f, rcpf(1.0f + Et), -1.0f);
            out[(size_t)(blockIdx.x * kNB + bb) * 6 + r]     = accP;
            out[(size_t)(blockIdx.x * kNB + bb) * 6 + 3 + r] = accO;
        }
    }
}

extern "C" void kernel_launch(void* const* d_in, const int* in_sizes, int n_in,
                              void* d_out, int out_size, void* d_ws, size_t ws_size,
                              hipStream_t stream) {
    const float* x    = (const float*)d_in[0];
    const float* Wih  = (const float*)d_in[1];
    const float* Whh  = (const float*)d_in[2];
    const float* bih  = (const float*)d_in[3];
    const float* bhh  = (const float*)d_in[4];
    const float* Wp   = (const float*)d_in[5];
    const float* bpos = (const float*)d_in[6];
    const float* Wo   = (const float*)d_in[7];
    const float* bori = (const float*)d_in[8];
    float* out = (float*)d_out;

    const int B = in_sizes[0] / (kT * kH);   // 2048
    lstm_rr8<<<dim3(B / kNB), dim3(512), 0, stream>>>(x, Wih, Whh, bih, bhh,
                                                      Wp, bpos, Wo, bori, out);
}

// Round 7
// 303.543 us; speedup vs baseline: 1.0285x; 1.0285x over previous
//
#include <hip/hip_runtime.h>
#include <math.h>

typedef _Float16 f16x8 __attribute__((ext_vector_type(8)));
typedef float    f32x4 __attribute__((ext_vector_type(4)));

constexpr int kT     = 512;   // sequence length
constexpr int kH     = 16;    // hidden
constexpr int kL     = 8;     // layers
constexpr int kNB    = 4;     // batches per block -> 512 blocks = 2 per CU
constexpr int kSlots = 8;     // ring depth = 2 epochs x 4 walls
constexpr int kLyr   = kL + 1;            // region 0 = x, region l+1 = layer l h
constexpr int kRows  = 5;     // 4 batch rows + permanent zero row
constexpr int kRowE  = 16;    // f16 per row (32 B; 2-way aliasing = free)
constexpr int kSE    = kLyr * kRows * kRowE;   // 720 f16 = 1440 B per slot
constexpr int kEpochs= 136;   // 544 walls >= last useful wall 539

constexpr float kL2E = 1.4426950408889634f;

__device__ __forceinline__ float ex2(float w)  { return __builtin_amdgcn_exp2f(w); }
__device__ __forceinline__ float rcpf(float e) { return __builtin_amdgcn_rcpf(e); }

// Round-16: 4-step barrier epochs + dual dephased blocks per CU.
//  - 8 waves = 8 layers; block = 4 batches; 512 blocks (2 blocks/CU ->
//    4 waves/SIMD, and the two blocks' barriers interleave: one block's
//    barrier wait is filled by the other block's compute)
//  - skew 4 per layer: layer l at epoch e computes t = 4(e-l)+j, j=0..3;
//    ONE barrier per epoch (136 total, was 528)
//  - within-epoch recurrence: h written b16 then B2 re-read b128 by the
//    SAME wave (per-wave in-order DS, proven in R12); B2 carried in
//    registers across the barrier (step 0 uses last epoch's final read)
//  - ring: slot = t & 7; phase (e-l)&1 selects slots 0-3 / 4-7, tracked by
//    sOfs ^= 4*kSE per epoch. Reader (l+1) reads opposite phase -> no race.
//  - fragment map = R12 (verified absmax 0): A wrow=(n&3)*16+(n>>2)+4*(q>>1)+8T,
//    bact=((q>>1)==g2), zero row 4; lane owns cell (unit q+4*g2+8*hi, batch n&3)
//  - 7-trans activation with clamps (verified R11/R14)
__global__ __launch_bounds__(512, 4)
void lstm_e4(const float* __restrict__ x,
             const float* __restrict__ Wih, const float* __restrict__ Whh,
             const float* __restrict__ bih, const float* __restrict__ bhh,
             const float* __restrict__ Wp,  const float* __restrict__ bpos,
             const float* __restrict__ Wo,  const float* __restrict__ bori,
             float* __restrict__ out)
{
    const int tid  = threadIdx.x;
    const int l    = tid >> 6;        // wave = layer
    const int lane = tid & 63;
    const int n    = lane & 15;
    const int q    = lane >> 4;
    const int bl   = n & 3;           // batch within block
    const int g2   = (n >> 2) & 1;    // diag-block selector
    const int hi   = n >> 3;          // own-tile select bit
    const bool bact = ((q >> 1) == g2);

    __shared__ __align__(16) _Float16 hb[kSlots][kLyr][kRows][kRowE]; // 11520 B

    {   // zero-init LDS
        int* hz = (int*)&hb[0][0][0][0];
        for (int i = tid; i < (int)(sizeof(hb) / 4); i += 512) hz[i] = 0;
    }
    __syncthreads();

    // ---- A fragments (both tiles) + scaled bias C-init (R12 verbatim) ----
    const float asc = ((n & 3) == 2) ? (-2.0f * kL2E) : (-kL2E);
    auto loadA = [&](const float* W, int T) -> f16x8 {
        const int wrow = (n & 3) * 16 + (n >> 2) + 4 * (q >> 1) + 8 * T;
        const float* src = W + (size_t)l * 64 * kH + wrow * kH;
        f16x8 a;
        #pragma unroll
        for (int j = 0; j < 8; ++j)
            a[j] = (_Float16)(asc * src[(q & 1) * 8 + j]);
        return a;
    };
    const f16x8 A1T0 = loadA(Wih, 0), A1T1 = loadA(Wih, 1);
    const f16x8 A2T0 = loadA(Whh, 0), A2T1 = loadA(Whh, 1);

    const int u0b = q + 4 * g2;
    f32x4 biasT0, biasT1;
    #pragma unroll
    for (int r = 0; r < 4; ++r) {
        const float sc = (r == 2) ? (-2.0f * kL2E) : (-kL2E);
        const int g0 = l * 64 + r * 16 + u0b;
        biasT0[r] = sc * (bih[g0] + bhh[g0]);
        biasT1[r] = sc * (bih[g0 + 8] + bhh[g0 + 8]);
    }

    // ---- LDS pointers ----
    const int boff = (bact ? bl * kRowE : 4 * kRowE) + (q & 1) * 8;
    const _Float16* b1b = &hb[0][l    ][0][0] + boff;   // upstream h / x
    const _Float16* b2b = &hb[0][l + 1][0][0] + boff;   // own h (self-read)
    const int um = u0b + 8 * hi;                        // lane's own unit
    _Float16* hw = &hb[0][l + 1][bl][um];               // h publish (b16)
    _Float16* xw = &hb[0][0][bl][um];                   // x publish (b16)

    // ---- x staging (wave 0): slot t&7 holds x(t). Prime x(0..7) into
    //      slots 0..7; regs xr[j] = x(8+j). Per epoch: write xr (t+8 of the
    //      slots just read), reload xr = x(t+12). 1-epoch load-to-use. ----
    const float* xg = x + ((size_t)(blockIdx.x * kNB + bl) * kT) * kH + um;
    float xr[4] = {0.f, 0.f, 0.f, 0.f};
    if (l == 0) {
        #pragma unroll
        for (int t = 0; t < 8; ++t)
            hb[t][0][bl][um] = (_Float16)xg[(size_t)t * kH];
        #pragma unroll
        for (int j = 0; j < 4; ++j)
            xr[j] = xg[(size_t)(8 + j) * kH];
    }
    // (no barrier needed: only wave 0 touches region 0; others read
    //  zero-init'd regions already fenced by the __syncthreads above)

    f16x8 B2r;
    #pragma unroll
    for (int j = 0; j < 8; ++j) B2r[j] = (_Float16)0.f;
    float c0 = 0.f;
    int te   = -4 * l;                       // t of step j=0 this epoch
    int sOfs = (l & 1) ? 4 * kSE : 0;        // phase (e-l)&1 slot base

    #pragma unroll 1
    for (int ep = 0; ep < kEpochs; ++ep) {
        const _Float16* b1p = b1b + sOfs;
        const _Float16* b2p = b2b + sOfs;
        _Float16* hwp = hw + sOfs;
        _Float16* xwp = xw + sOfs;

        #pragma unroll
        for (int j = 0; j < 4; ++j) {
            const int t = te + j;
            const bool active = ((unsigned)t < (unsigned)kT);

            // B1(t): upstream h / x, written last epoch (barrier-fenced)
            const f16x8 B1 = *(const f16x8*)(b1p + j * kSE);

            // gates: d = A2*h(t-1) + (A1*B1 + bias)
            f32x4 dInT0 = __builtin_amdgcn_mfma_f32_16x16x32_f16(A1T0, B1, biasT0, 0, 0, 0);
            f32x4 dInT1 = __builtin_amdgcn_mfma_f32_16x16x32_f16(A1T1, B1, biasT1, 0, 0, 0);
            f32x4 dT0   = __builtin_amdgcn_mfma_f32_16x16x32_f16(A2T0, B2r, dInT0, 0, 0, 0);
            f32x4 dT1   = __builtin_amdgcn_mfma_f32_16x16x32_f16(A2T1, B2r, dInT1, 0, 0, 0);

            // lane's own tile (hi)
            f32x4 d;
            #pragma unroll
            for (int r = 0; r < 4; ++r) d[r] = hi ? dT1[r] : dT0[r];

            // ---- 7-trans cell update (verified algebra + clamps) ----
            const float Ei = ex2(fminf(d[0], 40.0f));
            const float Ef = ex2(fminf(d[1], 40.0f));
            const float Eg = ex2(fminf(d[2], 40.0f));
            const float Eo = ex2(fminf(d[3], 60.0f));
            const float Dg = 1.0f + Eg;
            const float Df = 1.0f + Ef;
            const float P1  = fmaf(Ei, Dg, Dg);       // Di*Dg
            const float den = Df * P1;                // Df*Di*Dg
            const float t2  = fmaf(-Eg, Df, Df);      // (1-Eg)*Df
            const float num = fmaf(c0, P1, t2);
            float cn = num * rcpf(den);               // sf*c + si*tanh(g)
            cn = active ? cn : 0.0f;
            c0 = cn;
            const float ac = fminf(cn * (-2.0f * kL2E), 60.0f);
            const float Ec = ex2(ac);
            const float Do = 1.0f + Eo;
            const float R2 = rcpf(fmaf(Do, Ec, Do));
            const float h0 = fmaf(-Ec, R2, R2);       // sig(o)*tanh(c)

            // publish h(t) -> slot t&7 (b16), then self-read B2 for t+1
            // (same wave wrote ALL 64 group cells; per-wave in-order DS)
            *(hwp + j * kSE) = (_Float16)h0;
            B2r = *(const f16x8*)(b2p + j * kSE);

            if (l == 0) {                 // x ring: read-before-write per slot
                *(xwp + j * kSE) = (_Float16)xr[j];        // x(t+8)
                int ti = te + 12 + j; if (ti > kT - 1) ti = kT - 1;
                xr[j] = xg[(size_t)ti * kH];               // x(t+12)
            }
        }

        te += 4;
        sOfs ^= 4 * kSE;
        // one barrier per epoch: drain DS (h writes visible), vmcnt in flight
        asm volatile("s_waitcnt lgkmcnt(0)\n\ts_barrier" ::: "memory");
    }

    __syncthreads();

    // ---- head: layer-7 h(511) -> slot 511&7 = 7, region 8 ----
    if (l == kL - 1 && lane < 32) {
        const int bb = lane >> 3;         // batch 0..3
        const int r  = lane & 7;
        if (r < 6) {
            const bool  isP   = (r < 3);
            const float* wrow = isP ? (Wp + r * kH) : (Wo + (r - 3) * kH);
            float acc = isP ? bpos[r] : bori[r - 3];
            #pragma unroll
            for (int u = 0; u < kH; ++u)
                acc = fmaf((float)hb[7][kL][bb][u], wrow[u], acc);
            if (!isP) {
                const float Et = ex2(-2.0f * kL2E * acc);
                acc = fmaf(2.0f, rcpf(1.0f + Et), -1.0f);
            }
            out[(size_t)(blockIdx.x * kNB + bb) * 6 + r] = acc;
        }
    }
}

extern "C" void kernel_launch(void* const* d_in, const int* in_sizes, int n_in,
                              void* d_out, int out_size, void* d_ws, size_t ws_size,
                              hipStream_t stream) {
    const float* x    = (const float*)d_in[0];
    const float* Wih  = (const float*)d_in[1];
    const float* Whh  = (const float*)d_in[2];
    const float* bih  = (const float*)d_in[3];
    const float* bhh  = (const float*)d_in[4];
    const float* Wp   = (const float*)d_in[5];
    const float* bpos = (const float*)d_in[6];
    const float* Wo   = (const float*)d_in[7];
    const float* bori = (const float*)d_in[8];
    float* out = (float*)d_out;

    const int B = in_sizes[0] / (kT * kH);   // 2048
    lstm_e4<<<dim3(B / kNB), dim3(512), 0, stream>>>(x, Wih, Whh, bih, bhh,
                                                     Wp, bpos, Wo, bori, out);
}

// Round 8
// 279.110 us; speedup vs baseline: 1.1186x; 1.0875x over previous
//
#include <hip/hip_runtime.h>
#include <math.h>

typedef _Float16 f16x8 __attribute__((ext_vector_type(8)));
typedef float    f32x4 __attribute__((ext_vector_type(4)));

constexpr int kT    = 512;   // sequence length
constexpr int kH    = 16;    // hidden
constexpr int kL    = 8;     // layers
constexpr int kNB   = 8;     // batch per block
constexpr int kPad  = 24;    // f16 row stride (48 B)
constexpr int kRows = 9;     // 8 batch rows + permanent zero row
constexpr int kSlots= 16;    // ring depth
constexpr int kLyr  = kL + 1;               // lyr 0 = x, lyr 1+l = layer l h
constexpr int kSE   = kLyr * kRows * kPad;  // f16 elems per slot (1944)
constexpr int kIters= 33;    // 528 wall steps >= last useful wall 525

constexpr float kL2E = 1.4426950408889634f;

__device__ __forceinline__ float ex2(float w)  { return __builtin_amdgcn_exp2f(w); }
__device__ __forceinline__ float rcpf(float e) { return __builtin_amdgcn_rcpf(e); }

// Round-17: R11 (210us, verified) + post-barrier DS-burst halving.
//  - B1 is read at the END of wall s (last DS op, pinned by sched_barrier(0)),
//    carried across the barrier in registers; dIn is computed at the START of
//    wall s+1 as a register-only MFMA while B2 is in flight.
//  - post-barrier DS queue: 16 B2 b128 reads/CU (was 32 reads) -> last wave
//    starts its chain ~200 cy earlier.
//  - pre-barrier drain is counted: lgkmcnt(1) = h/x writes complete (in-order
//    DS), only the B1 read spans the barrier. Its slot (s&15, region l) was
//    written at wall s-1 and is not rewritten until wall s+15 -> race-free.
//  - everything else identical to R11: 16 waves (layer x tile), skew-2 ring,
//    7-trans activation with clamps, b16 h publish, x prefetch over vmcnt.
__global__ __launch_bounds__(1024, 4)
void lstm_w16b(const float* __restrict__ x,
               const float* __restrict__ Wih, const float* __restrict__ Whh,
               const float* __restrict__ bih, const float* __restrict__ bhh,
               const float* __restrict__ Wp,  const float* __restrict__ bpos,
               const float* __restrict__ Wo,  const float* __restrict__ bori,
               float* __restrict__ out)
{
    const int tid  = threadIdx.x;
    const int wv   = tid >> 6;
    const int l    = wv >> 1;
    const int T    = wv & 1;
    const int lane = tid & 63;
    const int n    = lane & 15;
    const int q    = lane >> 4;
    const int bn   = n & 7;
    const bool bact = ((q >> 1) == (n >> 3));

    __shared__ __align__(16) _Float16 hb[kSlots][kLyr][kRows][kPad];  // 62208 B

    {   // zero-init LDS
        int* hz = (int*)&hb[0][0][0][0];
        for (int i = tid; i < (int)(sizeof(hb) / 4); i += 1024) hz[i] = 0;
    }
    __syncthreads();

    // ---- A fragments, scaled; plain-layout column map u = (q&1)*8 + j ----
    const float asc = ((n & 3) == 2) ? (-2.0f * kL2E) : (-kL2E);
    auto loadA = [&](const float* W) -> f16x8 {
        const int wrow = (n & 3) * 16 + (n >> 2) + 4 * (q >> 1) + 8 * T;
        const float* src = W + (size_t)l * 64 * kH + wrow * kH;
        f16x8 a;
        #pragma unroll
        for (int j = 0; j < 8; ++j)
            a[j] = (_Float16)(asc * src[(q & 1) * 8 + j]);
        return a;
    };
    const f16x8 A1 = loadA(Wih);
    const f16x8 A2 = loadA(Whh);

    // ---- scaled bias as MFMA C-init: reg r = gate r, unit q+4*(n>>3)+8T ----
    const int u0 = q + 4 * (n >> 3) + 8 * T;    // this lane's single unit
    f32x4 bias;
    #pragma unroll
    for (int r = 0; r < 4; ++r) {
        const float sc = (r == 2) ? (-2.0f * kL2E) : (-kL2E);
        const int g0 = l * 64 + r * 16 + u0;
        bias[r] = sc * (bih[g0] + bhh[g0]);
    }

    // ---- LDS pointers (plain layout) ----
    const int boff = (bact ? bn * kPad : 8 * kPad) + (q & 1) * 8;
    const _Float16* b1b = &hb[0][l    ][0][0] + boff;   // v-input (x / h_{l-1})
    const _Float16* b2b = &hb[0][l + 1][0][0] + boff;   // own h
    _Float16* hw = &hb[0][l + 1][bn][u0];               // h publish (b16)

    // ---- x staging (layer-0 wave pair): lane covers batch lane>>3, unit xu
    //      slot k holds x(k+1); prime slots 15,0,1 with x(0..2);
    //      regs xa,xb,xc hold x(3),x(4),x(5) (3-wall load-to-use distance) ----
    const int xu = (lane & 7) + 8 * T;
    _Float16* xw = &hb[0][0][lane >> 3][xu];
    const float* xg_ptr =
        x + ((size_t)(blockIdx.x * kNB + (lane >> 3)) * kT) * kH;
    float xa = 0.f, xb = 0.f, xc = 0.f;
    if (l == 0) {
        #pragma unroll
        for (int t = 0; t < 3; ++t)
            *(xw + ((t + 15) & 15) * kSE) = (_Float16)xg_ptr[t * kH + xu];
        xa = xg_ptr[3 * kH + xu];
        xb = xg_ptr[4 * kH + xu];
        xc = xg_ptr[5 * kH + xu];
    }
    __syncthreads();

    // ---- prime: B1r = slot 15 (x(0) for l=0, zeros for l>0); dIn is
    //      computed from it at the top of wall 0. B2(t=-1) is read from the
    //      zero-initialized LDS at wall 0 (same zeros as a reg init). ----
    f16x8 B1r = *(const f16x8*)(b1b + 15 * kSE);

    float c0 = 0.f;               // plain (unscaled) cell state
    const int tl = 2 * l;

    #pragma unroll 1
    for (int it = 0; it < kIters; ++it) {
        const int sb = it * 16;
        #pragma unroll
        for (int k = 0; k < 16; ++k) {
            const int s = sb + k;
            const int slotR = k * kSE;
            const int slotW = ((k + 1) & 15) * kSE;
            const int slotX = ((k + 2) & 15) * kSE;
            const bool active = ((unsigned)(s - tl) < (unsigned)kT);

            // B2 = own h(t-1), slot s&15 (barrier-fenced) — the ONLY DS op
            // in the post-barrier burst; issued first.
            const f16x8 B2r = *(const f16x8*)(b2b + slotR);

            // dIn(t) from register-carried B1 (read last wall) — reg-only
            // MFMA, issues while B2 is in flight.
            f32x4 dIn = __builtin_amdgcn_mfma_f32_16x16x32_f16(A1, B1r, bias, 0, 0, 0);

            // recurrent half: d = A2*h(t-1) + dIn(t)  [waits only on B2]
            f32x4 d = __builtin_amdgcn_mfma_f32_16x16x32_f16(A2, B2r, dIn, 0, 0, 0);

            // ---- 7-trans cell update (verified algebra + clamps) ----
            const float Ei = ex2(fminf(d[0], 40.0f));   // e^-i
            const float Ef = ex2(fminf(d[1], 40.0f));   // e^-f
            const float Eg = ex2(fminf(d[2], 40.0f));   // e^-2g
            const float Eo = ex2(fminf(d[3], 60.0f));   // e^-o
            const float Dg = 1.0f + Eg;
            const float Df = 1.0f + Ef;
            const float P1  = fmaf(Ei, Dg, Dg);         // Di*Dg
            const float den = Df * P1;                  // Df*Di*Dg
            const float t2  = fmaf(-Eg, Df, Df);        // (1-Eg)*Df
            const float num = fmaf(c0, P1, t2);
            float cn = num * rcpf(den);                 // sf*c + si*tanh(g)
            cn = active ? cn : 0.0f;
            c0 = cn;
            const float ac = fminf(cn * (-2.0f * kL2E), 60.0f);
            const float Ec = ex2(ac);                   // e^-2c
            const float Do = 1.0f + Eo;
            const float R2 = rcpf(fmaf(Do, Ec, Do));    // 1/(Do*(1+Ec))
            const float h0 = fmaf(-Ec, R2, R2);         // sig(o)*tanh(c)

            // publish h(t) -> slot s+1 (own recurrence + downstream + head)
            *(hw + slotW) = (_Float16)h0;

            if (l == 0) {                    // publish x(s+3), rotate prefetch
                *(xw + slotX) = (_Float16)xa;
                xa = xb; xb = xc;
                int tn = s + 6; if (tn > kT - 1) tn = kT - 1;
                xc = xg_ptr[(size_t)tn * kH + xu];
            }

            // pin ordering: B1 read must be the LAST DS op of the wall so the
            // counted drain below proves the h/x writes completed.
            __builtin_amdgcn_sched_barrier(0);

            // B1 for next wall's dIn: issued late, rides across the barrier
            // (slot s&15 region l is stable until wall s+15).
            B1r = *(const f16x8*)(b1b + slotR);

            // counted drain: h/x writes complete (in-order DS); B1 read
            // still outstanding. vmcnt NOT drained (x prefetch spans walls).
            asm volatile("s_waitcnt lgkmcnt(1)\n\ts_barrier" ::: "memory");
        }
    }

    __syncthreads();

    // ---- head: layer-7 h(511) written at wall 525 -> slot (525+1)&15 = 14 ----
    if (wv == 15) {
        const int bb = lane >> 3;
        const int r  = lane & 7;
        if (r < 6) {
            const bool  isP   = (r < 3);
            const float* wrow = isP ? (Wp + r * kH) : (Wo + (r - 3) * kH);
            float acc = isP ? bpos[r] : bori[r - 3];
            #pragma unroll
            for (int u = 0; u < kH; ++u)
                acc = fmaf((float)hb[14][kL][bb][u], wrow[u], acc);
            if (!isP) {
                const float Et = ex2(-2.0f * kL2E * acc);
                acc = fmaf(2.0f, rcpf(1.0f + Et), -1.0f);
            }
            out[(size_t)(blockIdx.x * kNB + bb) * 6 + r] = acc;
        }
    }
}

extern "C" void kernel_launch(void* const* d_in, const int* in_sizes, int n_in,
                              void* d_out, int out_size, void* d_ws, size_t ws_size,
                              hipStream_t stream) {
    const float* x    = (const float*)d_in[0];
    const float* Wih  = (const float*)d_in[1];
    const float* Whh  = (const float*)d_in[2];
    const float* bih  = (const float*)d_in[3];
    const float* bhh  = (const float*)d_in[4];
    const float* Wp   = (const float*)d_in[5];
    const float* bpos = (const float*)d_in[6];
    const float* Wo   = (const float*)d_in[7];
    const float* bori = (const float*)d_in[8];
    float* out = (float*)d_out;

    const int B = in_sizes[0] / (kT * kH);   // 2048
    lstm_w16b<<<dim3(B / kNB), dim3(1024), 0, stream>>>(x, Wih, Whh, bih, bhh,
                                                        Wp, bpos, Wo, bori, out);
}